// Round 1
// baseline (339.507 us; speedup 1.0000x reference)
//
#include <hip/hip_runtime.h>
#include <math.h>

#define HW      3136      // 56*56
#define WIDTH   56
#define PADW    58
#define K_REM   1568      // round(3136 * 0.5)
#define NBATCH  32
#define NCHAN   256

// ---------------- Kernel 1: channel max/mean pooling ----------------
// x: [32][256][56][56] f32.  pooled: [32][2][3136] (ch0 = max, ch1 = mean)
__global__ __launch_bounds__(256) void pool_kernel(const float* __restrict__ x,
                                                   float* __restrict__ pooled) {
    int i4  = blockIdx.x * 256 + threadIdx.x;   // 0 .. 32*784
    int b   = i4 / 784;
    int hw4 = i4 - b * 784;
    const float4* px = (const float4*)x + (size_t)b * NCHAN * 784 + hw4;

    float4 mx = px[0];
    float4 s[8];
#pragma unroll
    for (int j = 0; j < 8; ++j) s[j] = make_float4(0.f, 0.f, 0.f, 0.f);

#pragma unroll 8
    for (int c = 0; c < NCHAN; ++c) {
        float4 v = px[(size_t)c * 784];
        mx.x = fmaxf(mx.x, v.x); mx.y = fmaxf(mx.y, v.y);
        mx.z = fmaxf(mx.z, v.z); mx.w = fmaxf(mx.w, v.w);
        float4* a = &s[c & 7];
        a->x += v.x; a->y += v.y; a->z += v.z; a->w += v.w;
    }
    // pairwise-ish combine (reduces accumulated rounding error)
    float4 t0, t1, t2, t3, u0, u1, sum;
    t0.x=s[0].x+s[1].x; t0.y=s[0].y+s[1].y; t0.z=s[0].z+s[1].z; t0.w=s[0].w+s[1].w;
    t1.x=s[2].x+s[3].x; t1.y=s[2].y+s[3].y; t1.z=s[2].z+s[3].z; t1.w=s[2].w+s[3].w;
    t2.x=s[4].x+s[5].x; t2.y=s[4].y+s[5].y; t2.z=s[4].z+s[5].z; t2.w=s[4].w+s[5].w;
    t3.x=s[6].x+s[7].x; t3.y=s[6].y+s[7].y; t3.z=s[6].z+s[7].z; t3.w=s[6].w+s[7].w;
    u0.x=t0.x+t1.x; u0.y=t0.y+t1.y; u0.z=t0.z+t1.z; u0.w=t0.w+t1.w;
    u1.x=t2.x+t3.x; u1.y=t2.y+t3.y; u1.z=t2.z+t3.z; u1.w=t2.w+t3.w;
    const float inv = 1.0f / 256.0f;
    sum.x=(u0.x+u1.x)*inv; sum.y=(u0.y+u1.y)*inv; sum.z=(u0.z+u1.z)*inv; sum.w=(u0.w+u1.w)*inv;

    float4* po = (float4*)pooled;
    po[(size_t)b * 1568 + hw4]       = mx;   // channel 0: max
    po[(size_t)b * 1568 + 784 + hw4] = sum;  // channel 1: mean
}

// ---------------- Kernel 2: conv3x3 + sigmoid + exact top-k zeroing ----------------
// one block per batch image
__global__ __launch_bounds__(256) void select_kernel(const float* __restrict__ pooled,
                                                     const float* __restrict__ w,
                                                     float* __restrict__ plane) {
    const int b   = blockIdx.x;
    const int tid = threadIdx.x;

    __shared__ float sm0[PADW * PADW];   // max channel, zero-padded 58x58
    __shared__ float sm1[PADW * PADW];   // mean channel
    __shared__ float yv[HW];             // sigmoid outputs
    __shared__ unsigned hist[256];
    __shared__ unsigned scanbuf[256];
    __shared__ unsigned sh_prefix;
    __shared__ int      sh_r;
    __shared__ unsigned sh_ce;

    for (int i = tid; i < PADW * PADW; i += 256) { sm0[i] = 0.f; sm1[i] = 0.f; }
    if (tid == 0) { sh_prefix = 0u; sh_r = K_REM - 1; sh_ce = 0u; }
    __syncthreads();

    const float* pb = pooled + (size_t)b * 2 * HW;
    for (int i = tid; i < HW; i += 256) {
        int r = i / WIDTH, c = i - r * WIDTH;
        sm0[(r + 1) * PADW + (c + 1)] = pb[i];
        sm1[(r + 1) * PADW + (c + 1)] = pb[HW + i];
    }
    float wreg[18];
#pragma unroll
    for (int j = 0; j < 18; ++j) wreg[j] = w[j];
    __syncthreads();

    // conv 3x3 (cross-correlation, pad=1) + sigmoid
    for (int i = tid; i < HW; i += 256) {
        int r = i / WIDTH, c = i - r * WIDTH;
        float acc = 0.f;
#pragma unroll
        for (int kr = 0; kr < 3; ++kr)
#pragma unroll
            for (int kc = 0; kc < 3; ++kc) {
                acc += wreg[kr * 3 + kc]     * sm0[(r + kr) * PADW + (c + kc)];
                acc += wreg[9 + kr * 3 + kc] * sm1[(r + kr) * PADW + (c + kc)];
            }
        yv[i] = 1.0f / (1.0f + expf(-acc));
    }
    __syncthreads();

    // ---- radix select: find bit pattern T of the (K_REM-1)-th smallest value
    // (values are sigmoid outputs > 0, so uint bit order == float order)
    for (int round = 0; round < 4; ++round) {
        hist[tid] = 0u;
        __syncthreads();
        const int shift = 24 - 8 * round;
        const unsigned pref = sh_prefix;
        for (int i = tid; i < HW; i += 256) {
            unsigned bits = __float_as_uint(yv[i]);
            bool cand = (round == 0) || ((bits >> (shift + 8)) == pref);
            if (cand) atomicAdd(&hist[(bits >> shift) & 255u], 1u);
        }
        __syncthreads();
        // inclusive scan over 256 bins (Hillis-Steele in LDS)
        unsigned h = hist[tid];
        scanbuf[tid] = h;
        __syncthreads();
        for (int off = 1; off < 256; off <<= 1) {
            unsigned add = (tid >= off) ? scanbuf[tid - off] : 0u;
            __syncthreads();
            scanbuf[tid] += add;
            __syncthreads();
        }
        unsigned incl = scanbuf[tid];
        unsigned excl = incl - h;
        int r = sh_r;
        __syncthreads();
        if ((int)excl <= r && r < (int)incl) {   // exactly one thread
            sh_r = r - (int)excl;
            sh_prefix = (pref << 8) | (unsigned)tid;
        }
        __syncthreads();
    }

    const unsigned T = sh_prefix;   // full 32-bit pattern of boundary value
    const int rfin   = sh_r;        // its index-rank within the ==T tie group

    // count ties (almost always 1)
    unsigned ce_local = 0;
    for (int i = tid; i < HW; i += 256)
        ce_local += (__float_as_uint(yv[i]) == T) ? 1u : 0u;
    if (ce_local) atomicAdd(&sh_ce, ce_local);
    __syncthreads();
    const unsigned ce = sh_ce;

    float* pl = plane + (size_t)b * HW;
    for (int i = tid; i < HW; i += 256) {
        float v = yv[i];
        unsigned bits = __float_as_uint(v);
        if (bits < T) {
            v = 0.f;
        } else if (bits == T) {
            if (ce == 1u) {
                v = 0.f;            // the boundary element itself is removed
            } else {
                // stable argsort tie-break: zero the first (rfin+1) ties by index
                int cnt = 0;
                for (int j = 0; j < i; ++j)
                    cnt += (__float_as_uint(yv[j]) == T) ? 1 : 0;
                if (cnt <= rfin) v = 0.f;
            }
        }
        pl[i] = v;
    }
}

// ---------------- Kernel 3: broadcast plane to 256 channels ----------------
__global__ __launch_bounds__(256) void bcast_kernel(const float* __restrict__ plane,
                                                    float4* __restrict__ out) {
    int i   = blockIdx.x * 256 + threadIdx.x;  // 0 .. 32*256*784
    int hw4 = i % 784;
    int bc  = i / 784;
    int b   = bc >> 8;
    out[i] = ((const float4*)plane)[b * 784 + hw4];
}

extern "C" void kernel_launch(void* const* d_in, const int* in_sizes, int n_in,
                              void* d_out, int out_size, void* d_ws, size_t ws_size,
                              hipStream_t stream) {
    const float* x = (const float*)d_in[0];
    const float* w = (const float*)d_in[1];
    float* out     = (float*)d_out;

    float* pooled = (float*)d_ws;                       // 32*2*3136 floats
    float* plane  = pooled + (size_t)NBATCH * 2 * HW;   // 32*3136 floats

    pool_kernel  <<<98,    256, 0, stream>>>(x, pooled);
    select_kernel<<<NBATCH,256, 0, stream>>>(pooled, w, plane);
    bcast_kernel <<<25088, 256, 0, stream>>>(plane, (float4*)out);
}

// Round 2
// 202.342 us; speedup vs baseline: 1.6779x; 1.6779x over previous
//
#include <hip/hip_runtime.h>
#include <math.h>

#define HW      3136      // 56*56
#define WIDTH   56
#define PADW    58
#define K_REM   1568      // round(3136 * 0.5)
#define NBATCH  32
#define NCHAN   256
#define NOWN    13        // ceil(3136 / 256)

// ---------------- Kernel 1: channel max/mean pooling (scalar, exact order) ----------------
// x: [32][256][56][56] f32.  pooled: [32][2][3136] (ch0 = max, ch1 = mean)
// NOTE: per-pixel accumulation sequence is bit-identical to the validated float4 version.
__global__ __launch_bounds__(256) void pool_kernel(const float* __restrict__ x,
                                                   float* __restrict__ pooled) {
    int p  = blockIdx.x * 256 + threadIdx.x;   // 0 .. 32*3136-1
    int b  = p / HW;
    int hw = p - b * HW;
    const float* px = x + (size_t)b * NCHAN * HW + hw;

    float mx = px[0];
    float s[8];
#pragma unroll
    for (int j = 0; j < 8; ++j) s[j] = 0.f;

#pragma unroll 16
    for (int c = 0; c < NCHAN; ++c) {
        float v = px[(size_t)c * HW];
        mx = fmaxf(mx, v);
        s[c & 7] += v;
    }
    float t0 = s[0] + s[1], t1 = s[2] + s[3], t2 = s[4] + s[5], t3 = s[6] + s[7];
    float u0 = t0 + t1, u1 = t2 + t3;
    float mean = (u0 + u1) * (1.0f / 256.0f);

    pooled[(size_t)b * 2 * HW + hw]      = mx;
    pooled[(size_t)b * 2 * HW + HW + hw] = mean;
}

// ---------------- Kernel 2: conv3x3 + sigmoid + exact top-k zeroing ----------------
// one block per batch image; histogram-free bitwise binary-search select
__global__ __launch_bounds__(256) void select_kernel(const float* __restrict__ pooled,
                                                     const float* __restrict__ w,
                                                     float* __restrict__ plane) {
    const int b   = blockIdx.x;
    const int tid = threadIdx.x;

    __shared__ float sm0[PADW * PADW];   // max channel, zero-padded 58x58
    __shared__ float sm1[PADW * PADW];   // mean channel
    __shared__ float yvs[HW];            // sigmoid outputs (for rare tie resolution)
    __shared__ int   wsum[2][4];         // parity-double-buffered wave partials

    for (int i = tid; i < PADW * PADW; i += 256) { sm0[i] = 0.f; sm1[i] = 0.f; }
    __syncthreads();

    const float* pb = pooled + (size_t)b * 2 * HW;
    for (int i = tid; i < HW; i += 256) {
        int r = i / WIDTH, c = i - r * WIDTH;
        sm0[(r + 1) * PADW + (c + 1)] = pb[i];
        sm1[(r + 1) * PADW + (c + 1)] = pb[HW + i];
    }
    float wreg[18];
#pragma unroll
    for (int j = 0; j < 18; ++j) wreg[j] = w[j];
    __syncthreads();

    // conv 3x3 (cross-correlation, pad=1) + sigmoid; values kept in registers
    float    val[NOWN];
    unsigned bits[NOWN];
#pragma unroll
    for (int t = 0; t < NOWN; ++t) {
        int i = tid + 256 * t;
        if (i < HW) {
            int r = i / WIDTH, c = i - r * WIDTH;
            float acc = 0.f;
#pragma unroll
            for (int kr = 0; kr < 3; ++kr)
#pragma unroll
                for (int kc = 0; kc < 3; ++kc) {
                    acc += wreg[kr * 3 + kc]     * sm0[(r + kr) * PADW + (c + kc)];
                    acc += wreg[9 + kr * 3 + kc] * sm1[(r + kr) * PADW + (c + kc)];
                }
            float v = 1.0f / (1.0f + expf(-acc));
            val[t]  = v;
            bits[t] = __float_as_uint(v);
            yvs[i]  = v;
        } else {
            val[t]  = 0.f;
            bits[t] = 0x7FFFFFFFu;   // never < cand, never == T
        }
    }
    __syncthreads();

    const int wid  = tid >> 6;
    const int lane = tid & 63;
    const int r    = K_REM - 1;      // 0-indexed rank of the boundary value

    // bitwise binary search for T = r-th smallest bit pattern
    // (sigmoid outputs are positive floats: uint order == float order; bits <= 0x3F800000)
    unsigned prefix = 0u;
    for (int bit = 29; bit >= 0; --bit) {
        unsigned cand = prefix | (1u << bit);
        int lc = 0;
#pragma unroll
        for (int t = 0; t < NOWN; ++t) lc += (bits[t] < cand) ? 1 : 0;
#pragma unroll
        for (int off = 32; off >= 1; off >>= 1) lc += __shfl_xor(lc, off);
        int par = bit & 1;
        if (lane == 0) wsum[par][wid] = lc;
        __syncthreads();
        int c = wsum[par][0] + wsum[par][1] + wsum[par][2] + wsum[par][3];
        if (c <= r) prefix = cand;   // wave-uniform decision, same on all threads
    }
    const unsigned T = prefix;

    // one more counting pass: cLess = #(v < T), ce = #(v == T), packed in one reduce
    {
        int lc = 0;
#pragma unroll
        for (int t = 0; t < NOWN; ++t) {
            lc += (bits[t] < T)  ? 1 : 0;
            lc += (bits[t] == T) ? (1 << 16) : 0;
        }
#pragma unroll
        for (int off = 32; off >= 1; off >>= 1) lc += __shfl_xor(lc, off);
        if (lane == 0) wsum[0][wid] = lc;
        __syncthreads();
    }
    int packed = wsum[0][0] + wsum[0][1] + wsum[0][2] + wsum[0][3];
    int cLess  = packed & 0xFFFF;
    int ce     = packed >> 16;
    int rfin   = r - cLess;          // index-rank within the ==T tie group to remove

    float* pl = plane + (size_t)b * HW;
#pragma unroll
    for (int t = 0; t < NOWN; ++t) {
        int i = tid + 256 * t;
        if (i >= HW) break;
        float v = val[t];
        unsigned bt = bits[t];
        if (bt < T) {
            v = 0.f;
        } else if (bt == T) {
            if (ce == 1) {
                v = 0.f;             // the boundary element itself is removed
            } else {
                // stable argsort tie-break: zero the first (rfin+1) ties by index
                int cnt = 0;
                for (int j = 0; j < i; ++j)
                    cnt += (__float_as_uint(yvs[j]) == T) ? 1 : 0;
                if (cnt <= rfin) v = 0.f;
            }
        }
        pl[i] = v;
    }
}

// ---------------- Kernel 3: broadcast plane to 256 channels ----------------
__global__ __launch_bounds__(256) void bcast_kernel(const float* __restrict__ plane,
                                                    float4* __restrict__ out) {
    int i   = blockIdx.x * 256 + threadIdx.x;  // 0 .. 32*256*784
    int hw4 = i % 784;
    int bc  = i / 784;
    int b   = bc >> 8;
    out[i] = ((const float4*)plane)[b * 784 + hw4];
}

extern "C" void kernel_launch(void* const* d_in, const int* in_sizes, int n_in,
                              void* d_out, int out_size, void* d_ws, size_t ws_size,
                              hipStream_t stream) {
    const float* x = (const float*)d_in[0];
    const float* w = (const float*)d_in[1];
    float* out     = (float*)d_out;

    float* pooled = (float*)d_ws;                       // 32*2*3136 floats
    float* plane  = pooled + (size_t)NBATCH * 2 * HW;   // 32*3136 floats

    pool_kernel  <<<392,   256, 0, stream>>>(x, pooled);
    select_kernel<<<NBATCH,256, 0, stream>>>(pooled, w, plane);
    bcast_kernel <<<25088, 256, 0, stream>>>(plane, (float4*)out);
}

// Round 3
// 201.554 us; speedup vs baseline: 1.6844x; 1.0039x over previous
//
#include <hip/hip_runtime.h>
#include <math.h>

#define HW      3136      // 56*56
#define WIDTH   56
#define PADW    58
#define K_REM   1568      // round(3136 * 0.5)
#define NBATCH  32
#define NCHAN   256
#define NOWN    13        // ceil(3136 / 256)

// ---------------- Kernel 1: channel max/mean pooling ----------------
// x: [32][256][56][56] f32.  pooled: [32][2][3136] (ch0 = max, ch1 = mean)
// 512-thread blocks: 8 waves, wave j sums channels c ≡ j (mod 8) in ascending
// order == the validated s[c&7] accumulators; combined in the identical tree
// (t0=s0+s1, ..., mean=(u0+u1)/256) -> bit-exact vs the passing version.
// Each wave covers 64 consecutive pixels -> 256B coalesced loads.
__global__ __launch_bounds__(512) void pool_kernel(const float* __restrict__ x,
                                                   float* __restrict__ pooled) {
    __shared__ float smax[8][64];
    __shared__ float ssum[8][64];

    const int tid  = threadIdx.x;
    const int lane = tid & 63;
    const int wv   = tid >> 6;             // 0..7 = channel class
    const int blk  = blockIdx.x;           // 0..1567
    const int b    = blk / 49;
    const int hw   = (blk - b * 49) * 64 + lane;

    const float* px = x + (size_t)b * NCHAN * HW + hw;

    float mxl = px[(size_t)wv * HW];       // first channel of this class
    float sl  = 0.f;
#pragma unroll 8
    for (int k = 0; k < 32; ++k) {
        float v = px[(size_t)(wv + 8 * k) * HW];
        mxl = fmaxf(mxl, v);
        sl += v;
    }
    smax[wv][lane] = mxl;
    ssum[wv][lane] = sl;
    __syncthreads();

    if (wv == 0) {
        // max: fmaxf is order-insensitive (exact)
        float m0 = fmaxf(smax[0][lane], smax[1][lane]);
        float m1 = fmaxf(smax[2][lane], smax[3][lane]);
        float m2 = fmaxf(smax[4][lane], smax[5][lane]);
        float m3 = fmaxf(smax[6][lane], smax[7][lane]);
        float m  = fmaxf(fmaxf(m0, m1), fmaxf(m2, m3));
        // mean: identical combine tree as the validated kernel
        float t0 = ssum[0][lane] + ssum[1][lane];
        float t1 = ssum[2][lane] + ssum[3][lane];
        float t2 = ssum[4][lane] + ssum[5][lane];
        float t3 = ssum[6][lane] + ssum[7][lane];
        float u0 = t0 + t1, u1 = t2 + t3;
        float mean = (u0 + u1) * (1.0f / 256.0f);

        pooled[(size_t)b * 2 * HW + hw]      = m;
        pooled[(size_t)b * 2 * HW + HW + hw] = mean;
    }
}

// ---------------- Kernel 2: conv3x3 + sigmoid + exact top-k zeroing ----------------
// one block per batch image; histogram-free bitwise binary-search select
__global__ __launch_bounds__(256) void select_kernel(const float* __restrict__ pooled,
                                                     const float* __restrict__ w,
                                                     float* __restrict__ plane) {
    const int b   = blockIdx.x;
    const int tid = threadIdx.x;

    __shared__ float sm0[PADW * PADW];   // max channel, zero-padded 58x58
    __shared__ float sm1[PADW * PADW];   // mean channel
    __shared__ float yvs[HW];            // sigmoid outputs (for rare tie resolution)
    __shared__ int   wsum[2][4];         // parity-double-buffered wave partials

    for (int i = tid; i < PADW * PADW; i += 256) { sm0[i] = 0.f; sm1[i] = 0.f; }
    __syncthreads();

    const float* pb = pooled + (size_t)b * 2 * HW;
    for (int i = tid; i < HW; i += 256) {
        int r = i / WIDTH, c = i - r * WIDTH;
        sm0[(r + 1) * PADW + (c + 1)] = pb[i];
        sm1[(r + 1) * PADW + (c + 1)] = pb[HW + i];
    }
    float wreg[18];
#pragma unroll
    for (int j = 0; j < 18; ++j) wreg[j] = w[j];
    __syncthreads();

    // conv 3x3 (cross-correlation, pad=1) + sigmoid; values kept in registers
    float    val[NOWN];
    unsigned bits[NOWN];
#pragma unroll
    for (int t = 0; t < NOWN; ++t) {
        int i = tid + 256 * t;
        if (i < HW) {
            int r = i / WIDTH, c = i - r * WIDTH;
            float acc = 0.f;
#pragma unroll
            for (int kr = 0; kr < 3; ++kr)
#pragma unroll
                for (int kc = 0; kc < 3; ++kc) {
                    acc += wreg[kr * 3 + kc]     * sm0[(r + kr) * PADW + (c + kc)];
                    acc += wreg[9 + kr * 3 + kc] * sm1[(r + kr) * PADW + (c + kc)];
                }
            float v = 1.0f / (1.0f + expf(-acc));
            val[t]  = v;
            bits[t] = __float_as_uint(v);
            yvs[i]  = v;
        } else {
            val[t]  = 0.f;
            bits[t] = 0x7FFFFFFFu;   // never < cand, never == T
        }
    }
    __syncthreads();

    const int wid  = tid >> 6;
    const int lane = tid & 63;
    const int r    = K_REM - 1;      // 0-indexed rank of the boundary value

    // bitwise binary search for T = r-th smallest bit pattern
    // (sigmoid outputs are positive floats: uint order == float order; bits <= 0x3F800000)
    unsigned prefix = 0u;
    for (int bit = 29; bit >= 0; --bit) {
        unsigned cand = prefix | (1u << bit);
        int lc = 0;
#pragma unroll
        for (int t = 0; t < NOWN; ++t) lc += (bits[t] < cand) ? 1 : 0;
#pragma unroll
        for (int off = 32; off >= 1; off >>= 1) lc += __shfl_xor(lc, off);
        int par = bit & 1;
        if (lane == 0) wsum[par][wid] = lc;
        __syncthreads();
        int c = wsum[par][0] + wsum[par][1] + wsum[par][2] + wsum[par][3];
        if (c <= r) prefix = cand;   // wave-uniform decision, same on all threads
    }
    const unsigned T = prefix;

    // one more counting pass: cLess = #(v < T), ce = #(v == T), packed in one reduce
    {
        int lc = 0;
#pragma unroll
        for (int t = 0; t < NOWN; ++t) {
            lc += (bits[t] < T)  ? 1 : 0;
            lc += (bits[t] == T) ? (1 << 16) : 0;
        }
#pragma unroll
        for (int off = 32; off >= 1; off >>= 1) lc += __shfl_xor(lc, off);
        if (lane == 0) wsum[0][wid] = lc;
        __syncthreads();
    }
    int packed = wsum[0][0] + wsum[0][1] + wsum[0][2] + wsum[0][3];
    int cLess  = packed & 0xFFFF;
    int ce     = packed >> 16;
    int rfin   = r - cLess;          // index-rank within the ==T tie group to remove

    float* pl = plane + (size_t)b * HW;
#pragma unroll
    for (int t = 0; t < NOWN; ++t) {
        int i = tid + 256 * t;
        if (i >= HW) break;
        float v = val[t];
        unsigned bt = bits[t];
        if (bt < T) {
            v = 0.f;
        } else if (bt == T) {
            if (ce == 1) {
                v = 0.f;             // the boundary element itself is removed
            } else {
                // stable argsort tie-break: zero the first (rfin+1) ties by index
                int cnt = 0;
                for (int j = 0; j < i; ++j)
                    cnt += (__float_as_uint(yvs[j]) == T) ? 1 : 0;
                if (cnt <= rfin) v = 0.f;
            }
        }
        pl[i] = v;
    }
}

// ---------------- Kernel 3: broadcast plane to 256 channels ----------------
__global__ __launch_bounds__(256) void bcast_kernel(const float* __restrict__ plane,
                                                    float4* __restrict__ out) {
    int i   = blockIdx.x * 256 + threadIdx.x;  // 0 .. 32*256*784
    int hw4 = i % 784;
    int bc  = i / 784;
    int b   = bc >> 8;
    out[i] = ((const float4*)plane)[b * 784 + hw4];
}

extern "C" void kernel_launch(void* const* d_in, const int* in_sizes, int n_in,
                              void* d_out, int out_size, void* d_ws, size_t ws_size,
                              hipStream_t stream) {
    const float* x = (const float*)d_in[0];
    const float* w = (const float*)d_in[1];
    float* out     = (float*)d_out;

    float* pooled = (float*)d_ws;                       // 32*2*3136 floats
    float* plane  = pooled + (size_t)NBATCH * 2 * HW;   // 32*3136 floats

    pool_kernel  <<<1568,  512, 0, stream>>>(x, pooled);
    select_kernel<<<NBATCH,256, 0, stream>>>(pooled, w, plane);
    bcast_kernel <<<25088, 256, 0, stream>>>(plane, (float4*)out);
}